// Round 2
// baseline (204.916 us; speedup 1.0000x reference)
//
#include <hip/hip_runtime.h>

#define NB 32
#define NT 2048
#define ND 512
#define NDQ 128  // ND / 4 (float4 per row)

// ---------------------------------------------------------------------------
// Kernel 1: per-(batch, t-chunk) partial sums of x, |x|, x*w over the chunk.
// block = 256 threads = 2 token groups (tt) x 128 float4 lanes (dq).
// grid  = (NC, B). Each block reduces its 2 groups in LDS and writes ONE
// partial (3 x 512 floats) to workspace.
// ---------------------------------------------------------------------------
__global__ __launch_bounds__(256) void vu_partial_kernel(
    const float* __restrict__ vs,       // [B,T,D]
    const int* __restrict__ slen,       // [B]
    const int* __restrict__ wseq,       // [B,T]
    const float* __restrict__ weights,  // [VOCAB]
    float4* __restrict__ ps,            // [B*NC*NDQ] sum
    float4* __restrict__ pa,            // [B*NC*NDQ] sum |x|
    float4* __restrict__ pw,            // [B*NC*NDQ] sum x*w
    int NC)
{
    const int c   = blockIdx.x;
    const int b   = blockIdx.y;
    const int tid = threadIdx.x;
    const int dq  = tid & (NDQ - 1);
    const int tt  = tid >> 7;           // 0 or 1
    const int TC  = NT / NC;            // tokens per chunk

    __shared__ float w_lds[NT];         // per-token weight (max chunk = NT)
    __shared__ float red[NDQ * 12];     // cross-group reduce: 128 x 3 float4

    const int t0   = c * TC;
    const int len  = slen[b];
    const int tEnd = min(t0 + TC, len);

    // Stage per-token scalar weights into LDS (one gather per token).
    for (int i = tid; i < TC; i += 256) {
        const int t = t0 + i;
        float w = 0.0f;
        if (t < tEnd) w = weights[wseq[b * NT + t]];
        w_lds[i] = w;
    }
    __syncthreads();

    float4 s  = make_float4(0.f, 0.f, 0.f, 0.f);
    float4 sa = make_float4(0.f, 0.f, 0.f, 0.f);
    float4 sw = make_float4(0.f, 0.f, 0.f, 0.f);

    const float4* vsq = (const float4*)vs;
    // group tt handles tokens t0+tt, t0+tt+2, ... (stride 2)
    for (int t = t0 + tt; t < tEnd; t += 2) {
        const float4 v = vsq[((size_t)b * NT + t) * NDQ + dq];
        const float  w = w_lds[t - t0];
        s.x += v.x; s.y += v.y; s.z += v.z; s.w += v.w;
        sa.x += fabsf(v.x); sa.y += fabsf(v.y); sa.z += fabsf(v.z); sa.w += fabsf(v.w);
        sw.x += v.x * w; sw.y += v.y * w; sw.z += v.z * w; sw.w += v.w * w;
    }

    // combine the two token groups through LDS
    if (tt == 1) {
        float* r = &red[dq * 12];
        r[0] = s.x;  r[1] = s.y;  r[2]  = s.z;  r[3]  = s.w;
        r[4] = sa.x; r[5] = sa.y; r[6]  = sa.z; r[7]  = sa.w;
        r[8] = sw.x; r[9] = sw.y; r[10] = sw.z; r[11] = sw.w;
    }
    __syncthreads();
    if (tt == 0) {
        const float* r = &red[dq * 12];
        s.x += r[0];  s.y += r[1];  s.z += r[2];   s.w += r[3];
        sa.x += r[4]; sa.y += r[5]; sa.z += r[6];  sa.w += r[7];
        sw.x += r[8]; sw.y += r[9]; sw.z += r[10]; sw.w += r[11];
        const size_t o = ((size_t)b * NC + c) * NDQ + dq;
        ps[o] = s;
        pa[o] = sa;
        pw[o] = sw;
    }
}

// ---------------------------------------------------------------------------
// Kernel 2: fold the NC partials per (b,d) and emit y = s/sa and y_hat = sw.
// 4096 threads, one float4 column each. Coalesced reads (consecutive dq).
// ---------------------------------------------------------------------------
__global__ __launch_bounds__(256) void vu_reduce_kernel(
    const float4* __restrict__ ps,
    const float4* __restrict__ pa,
    const float4* __restrict__ pw,
    float4* __restrict__ out,           // [2][B][NDQ] float4
    int NC)
{
    const int gid = blockIdx.x * 256 + threadIdx.x;   // [0, B*NDQ)
    if (gid >= NB * NDQ) return;
    const int b  = gid >> 7;
    const int dq = gid & (NDQ - 1);

    float4 s  = make_float4(0.f, 0.f, 0.f, 0.f);
    float4 sa = make_float4(0.f, 0.f, 0.f, 0.f);
    float4 sw = make_float4(0.f, 0.f, 0.f, 0.f);
    for (int c = 0; c < NC; ++c) {
        const size_t o = ((size_t)b * NC + c) * NDQ + dq;
        const float4 a = ps[o];
        const float4 x = pa[o];
        const float4 w = pw[o];
        s.x += a.x; s.y += a.y; s.z += a.z; s.w += a.w;
        sa.x += x.x; sa.y += x.y; sa.z += x.z; sa.w += x.w;
        sw.x += w.x; sw.y += w.y; sw.z += w.z; sw.w += w.w;
    }
    float4 y;
    y.x = s.x / sa.x; y.y = s.y / sa.y; y.z = s.z / sa.z; y.w = s.w / sa.w;
    out[(size_t)b * NDQ + dq] = y;                       // y
    out[(size_t)NB * NDQ + (size_t)b * NDQ + dq] = sw;   // y_hat
}

extern "C" void kernel_launch(void* const* d_in, const int* in_sizes, int n_in,
                              void* d_out, int out_size, void* d_ws, size_t ws_size,
                              hipStream_t stream) {
    const float* vs      = (const float*)d_in[0];
    const int*   slen    = (const int*)d_in[1];
    const int*   wseq    = (const int*)d_in[2];
    const float* weights = (const float*)d_in[3];
    float4*      out     = (float4*)d_out;

    // Pick the largest NC (t-chunks) whose partials fit in the workspace.
    int NC = 64;
    while (NC > 1) {
        size_t need = (size_t)NB * NC * ND * 3 * sizeof(float);
        if (need <= ws_size) break;
        NC >>= 1;
    }

    const size_t stride = (size_t)NB * NC * NDQ;   // in float4 units
    float4* ps = (float4*)d_ws;
    float4* pa = ps + stride;
    float4* pw = pa + stride;

    dim3 g1(NC, NB);
    vu_partial_kernel<<<g1, 256, 0, stream>>>(vs, slen, wseq, weights, ps, pa, pw, NC);

    const int n2 = NB * NDQ;                       // 4096 threads
    vu_reduce_kernel<<<(n2 + 255) / 256, 256, 0, stream>>>(ps, pa, pw, out, NC);
}

// Round 4
// 204.547 us; speedup vs baseline: 1.0018x; 1.0018x over previous
//
#include <hip/hip_runtime.h>

#define NB 32
#define NT 2048
#define ND 512
#define NDQ 128   // ND / 4 (float4 per row)
#define NC 64     // t-chunks per batch
#define TC (NT / NC)   // 32 tokens per chunk

// ---------------------------------------------------------------------------
// Kernel 1: per-(batch, t-chunk) partial sums of x, |x|, x*w over the chunk.
// block = 128 threads = one float4 lane-set over D=512 (2 waves).
// grid = (NC, B). Blocks whose whole chunk is masked (t0 >= len) exit
// immediately WITHOUT writing -- kernel 2 only reads active chunks.
// ---------------------------------------------------------------------------
__global__ __launch_bounds__(128) void vu_partial_kernel(
    const float* __restrict__ vs,       // [B,T,D]
    const int* __restrict__ slen,       // [B]
    const int* __restrict__ wseq,       // [B,T]
    const float* __restrict__ weights,  // [VOCAB]
    float4* __restrict__ ps,            // [B*NC*NDQ] sum
    float4* __restrict__ pa,            // [B*NC*NDQ] sum |x|
    float4* __restrict__ pw)            // [B*NC*NDQ] sum x*w
{
    const int c  = blockIdx.x;
    const int b  = blockIdx.y;
    const int dq = threadIdx.x;         // 0..127

    const int t0   = c * TC;
    const int len  = slen[b];
    const int tEnd = min(t0 + TC, len);
    if (t0 >= tEnd) return;             // fully masked chunk: no write needed

    __shared__ float w_lds[TC];         // per-token scalar weight
    if (threadIdx.x < TC) {
        const int t = t0 + threadIdx.x;
        w_lds[threadIdx.x] = (t < tEnd) ? weights[wseq[b * NT + t]] : 0.0f;
    }
    __syncthreads();

    float4 s  = make_float4(0.f, 0.f, 0.f, 0.f);
    float4 sa = make_float4(0.f, 0.f, 0.f, 0.f);
    float4 sw = make_float4(0.f, 0.f, 0.f, 0.f);

    const float4* vsq = (const float4*)vs;
    #pragma unroll 4
    for (int t = t0; t < tEnd; ++t) {
        const float4 v = vsq[((size_t)b * NT + t) * NDQ + dq];
        const float  w = w_lds[t - t0];
        s.x += v.x; s.y += v.y; s.z += v.z; s.w += v.w;
        sa.x += fabsf(v.x); sa.y += fabsf(v.y); sa.z += fabsf(v.z); sa.w += fabsf(v.w);
        sw.x = fmaf(v.x, w, sw.x); sw.y = fmaf(v.y, w, sw.y);
        sw.z = fmaf(v.z, w, sw.z); sw.w = fmaf(v.w, w, sw.w);
    }

    const size_t o = ((size_t)b * NC + c) * NDQ + dq;
    ps[o] = s;
    pa[o] = sa;
    pw[o] = sw;
}

// ---------------------------------------------------------------------------
// Kernel 2: fold the ACTIVE partials per (b,d): y = s/sa, y_hat = sw.
// 4096 threads, one float4 column each; only reads chunks c < ceil(len/TC),
// so never touches unwritten (poisoned) workspace.
// ---------------------------------------------------------------------------
__global__ __launch_bounds__(256) void vu_reduce_kernel(
    const float4* __restrict__ ps,
    const float4* __restrict__ pa,
    const float4* __restrict__ pw,
    const int* __restrict__ slen,
    float4* __restrict__ out)           // [2][B][NDQ] float4
{
    const int gid = blockIdx.x * 256 + threadIdx.x;   // [0, B*NDQ)
    if (gid >= NB * NDQ) return;
    const int b  = gid >> 7;
    const int dq = gid & (NDQ - 1);

    const int len  = slen[b];
    const int cEnd = (len + TC - 1) / TC;             // active chunks (>=1)

    float4 s  = make_float4(0.f, 0.f, 0.f, 0.f);
    float4 sa = make_float4(0.f, 0.f, 0.f, 0.f);
    float4 sw = make_float4(0.f, 0.f, 0.f, 0.f);
    for (int c = 0; c < cEnd; ++c) {
        const size_t o = ((size_t)b * NC + c) * NDQ + dq;
        const float4 a = ps[o];
        const float4 x = pa[o];
        const float4 w = pw[o];
        s.x += a.x; s.y += a.y; s.z += a.z; s.w += a.w;
        sa.x += x.x; sa.y += x.y; sa.z += x.z; sa.w += x.w;
        sw.x += w.x; sw.y += w.y; sw.z += w.z; sw.w += w.w;
    }
    float4 y;
    y.x = s.x / sa.x; y.y = s.y / sa.y; y.z = s.z / sa.z; y.w = s.w / sa.w;
    out[(size_t)b * NDQ + dq] = y;                       // y
    out[(size_t)NB * NDQ + (size_t)b * NDQ + dq] = sw;   // y_hat
}

extern "C" void kernel_launch(void* const* d_in, const int* in_sizes, int n_in,
                              void* d_out, int out_size, void* d_ws, size_t ws_size,
                              hipStream_t stream) {
    const float* vs      = (const float*)d_in[0];
    const int*   slen    = (const int*)d_in[1];
    const int*   wseq    = (const int*)d_in[2];
    const float* weights = (const float*)d_in[3];
    float4*      out     = (float4*)d_out;

    const size_t stride = (size_t)NB * NC * NDQ;   // float4 units per buffer
    float4* ps = (float4*)d_ws;
    float4* pa = ps + stride;
    float4* pw = pa + stride;

    dim3 g1(NC, NB);
    vu_partial_kernel<<<g1, 128, 0, stream>>>(vs, slen, wseq, weights, ps, pa, pw);

    const int n2 = NB * NDQ;                       // 4096 threads
    vu_reduce_kernel<<<(n2 + 255) / 256, 256, 0, stream>>>(ps, pa, pw, slen, out);
}